// Round 1
// baseline (647.208 us; speedup 1.0000x reference)
//
#include <hip/hip_runtime.h>

// Workspace layout (floats), written by prep_kernel each call.
// All weights pre-transposed to column-major so the inner "broadcast h_j,
// FMA into a[0..31]" form reads contiguous wave-uniform columns (-> s_load).
// W_ih, (b_ih+b_hh), W_hh are pre-scaled by K = 2*log2(e) so that
// tanh(a) = 1 - 2/(1 + exp2(K*a)) needs no per-element scaling.
#define OFF_WIH 0      // 32   : W_ih[k]*K
#define OFF_C   32     // 32   : (b_ih[k]+b_hh[k])*K
#define OFF_WHH 64     // 1024 : col-major W_hh[k][j]*K at [j*32 + k]
#define OFF_W1  1088   // 1536 : col-major W1[o][m]    at [m*16 + o]
#define OFF_B1  2624   // 16
#define OFF_W2  2640   // 128  : col-major W2[o][k]    at [k*8 + o]
#define OFF_B2  2768   // 8
#define OFF_W3  2776   // 8
#define OFF_B3  2784   // 1

__global__ void prep_kernel(const float* __restrict__ wih, const float* __restrict__ whh,
                            const float* __restrict__ bih, const float* __restrict__ bhh,
                            const float* __restrict__ w1,  const float* __restrict__ b1,
                            const float* __restrict__ w2,  const float* __restrict__ b2,
                            const float* __restrict__ w3,  const float* __restrict__ b3,
                            float* __restrict__ ws)
{
    const float K = 2.8853900817779268f; // 2*log2(e)
    const int t = threadIdx.x;
    if (t < 32) {
        ws[OFF_WIH + t] = wih[t] * K;
        ws[OFF_C   + t] = (bih[t] + bhh[t]) * K;
    }
    for (int i = t; i < 1024; i += 256) {          // W_hh [32,32] row-major -> col-major, scaled
        int r = i >> 5, c = i & 31;                // whh[r][c]
        ws[OFF_WHH + c * 32 + r] = whh[i] * K;
    }
    for (int i = t; i < 1536; i += 256) {          // W1 [16,96] -> col-major
        int o = i / 96, m = i - o * 96;
        ws[OFF_W1 + m * 16 + o] = w1[i];
    }
    if (t < 16) ws[OFF_B1 + t] = b1[t];
    for (int i = t; i < 128; i += 256) {           // W2 [8,16] -> col-major
        int o = i >> 4, k = i & 15;
        ws[OFF_W2 + k * 8 + o] = w2[i];
    }
    if (t < 8) { ws[OFF_B2 + t] = b2[t]; ws[OFF_W3 + t] = w3[t]; }
    if (t == 0) ws[OFF_B3] = b3[0];
}

// tanh(a) given ap = 2*log2(e)*a:  tanh(a) = 1 - 2/(exp2(ap)+1)
__device__ __forceinline__ float tanh_fast(float ap) {
    float e = __builtin_amdgcn_exp2f(ap);
    return fmaf(-2.0f, __builtin_amdgcn_rcpf(e + 1.0f), 1.0f);
}

__global__ __launch_bounds__(256)
void rnn_mlp_kernel(const float* __restrict__ x, const float* __restrict__ ws,
                    float* __restrict__ out, int B)
{
    const int i = blockIdx.x * 256 + threadIdx.x;
    if (i >= B) return;

    const float x1 = x[3 * i + 0];
    const float x2 = x[3 * i + 1];
    const float x3 = x[3 * i + 2];

    float h[32];
    float a[32];
    float f1[16];

    #pragma unroll
    for (int o = 0; o < 16; ++o) f1[o] = ws[OFF_B1 + o];

    #pragma unroll
    for (int t = 0; t < 3; ++t) {
        const float xv = (t == 0) ? x1 : ((t == 1) ? x2 : x3);

        // pre-activation (scaled by K): a = xv*Wih' + c'  (+ Whh'*h for t>0)
        #pragma unroll
        for (int k = 0; k < 32; ++k) a[k] = fmaf(xv, ws[OFF_WIH + k], ws[OFF_C + k]);

        if (t > 0) {
            #pragma unroll
            for (int j = 0; j < 32; ++j) {
                const float hj = h[j];
                #pragma unroll
                for (int k = 0; k < 32; ++k)
                    a[k] = fmaf(hj, ws[OFF_WHH + j * 32 + k], a[k]);
            }
        }

        #pragma unroll
        for (int k = 0; k < 32; ++k) h[k] = tanh_fast(a[k]);

        // fc1 accumulation: f1[o] += relu(h[j]) * W1[o][t*32+j]
        #pragma unroll
        for (int j = 0; j < 32; ++j) {
            const float r = fmaxf(h[j], 0.0f);
            #pragma unroll
            for (int o = 0; o < 16; ++o)
                f1[o] = fmaf(r, ws[OFF_W1 + (t * 32 + j) * 16 + o], f1[o]);
        }
    }

    // fc2 (16 -> 8) + relu
    float g[8];
    #pragma unroll
    for (int o = 0; o < 8; ++o) g[o] = ws[OFF_B2 + o];
    #pragma unroll
    for (int k = 0; k < 16; ++k) {
        const float v = f1[k];
        #pragma unroll
        for (int o = 0; o < 8; ++o)
            g[o] = fmaf(v, ws[OFF_W2 + k * 8 + o], g[o]);
    }

    // fc3 (8 -> 1)
    float y = ws[OFF_B3];
    #pragma unroll
    for (int o = 0; o < 8; ++o)
        y = fmaf(fmaxf(g[o], 0.0f), ws[OFF_W3 + o], y);

    out[i] = y;
}

extern "C" void kernel_launch(void* const* d_in, const int* in_sizes, int n_in,
                              void* d_out, int out_size, void* d_ws, size_t ws_size,
                              hipStream_t stream)
{
    const float* x   = (const float*)d_in[0];
    const float* wih = (const float*)d_in[1];
    const float* whh = (const float*)d_in[2];
    const float* bih = (const float*)d_in[3];
    const float* bhh = (const float*)d_in[4];
    const float* w1  = (const float*)d_in[5];
    const float* b1  = (const float*)d_in[6];
    const float* w2  = (const float*)d_in[7];
    const float* b2  = (const float*)d_in[8];
    const float* w3  = (const float*)d_in[9];
    const float* b3  = (const float*)d_in[10];
    float* out = (float*)d_out;
    float* ws  = (float*)d_ws;

    const int B = in_sizes[0] / 3;

    prep_kernel<<<1, 256, 0, stream>>>(wih, whh, bih, bhh, w1, b1, w2, b2, w3, b3, ws);
    rnn_mlp_kernel<<<(B + 255) / 256, 256, 0, stream>>>(x, ws, out, B);
}